// Round 7
// baseline (682.395 us; speedup 1.0000x reference)
//
#include <hip/hip_runtime.h>

#define BB  4
#define SS  512
#define JJ  24
#define HH  128
#define NHH 8
#define HSS 16

// ---------- bf16 helpers (used for LDS compression of weights/V only) ----------
__device__ __forceinline__ unsigned short f2b(float f) {
    unsigned u; __builtin_memcpy(&u, &f, 4);
    u += 0x7fffu + ((u >> 16) & 1u);          // RNE
    return (unsigned short)(u >> 16);
}
__device__ __forceinline__ void unpack2(unsigned u, float& lo, float& hi) {
    unsigned a = u << 16, b = u & 0xffff0000u;
    __builtin_memcpy(&lo, &a, 4); __builtin_memcpy(&hi, &b, 4);
}
// 16 bf16 weights (two uint4) FMA'd into acc[16] with scalar xv
__device__ __forceinline__ void fma16v(const uint4 w0, const uint4 w1, float xv, float* acc) {
    float wf[16];
    unpack2(w0.x, wf[0],  wf[1]);  unpack2(w0.y, wf[2],  wf[3]);
    unpack2(w0.z, wf[4],  wf[5]);  unpack2(w0.w, wf[6],  wf[7]);
    unpack2(w1.x, wf[8],  wf[9]);  unpack2(w1.y, wf[10], wf[11]);
    unpack2(w1.z, wf[12], wf[13]); unpack2(w1.w, wf[14], wf[15]);
#pragma unroll
    for (int d = 0; d < 16; ++d) acc[d] = fmaf(xv, wf[d], acc[d]);
}

// ---------- LN param staging with fallback (gamma=1, beta=0) ----------
__global__ __launch_bounds__(128) void ln_param_kernel(
        const float* __restrict__ g, const float* __restrict__ b,
        float* __restrict__ gws, float* __restrict__ bws) {
    int k = threadIdx.x;
    gws[k] = g ? g[k] : 1.0f;
    bws[k] = b ? b[k] : 0.0f;
}

// ---------- flash-softmax update ----------
__device__ __forceinline__ void attn_update(float* o, float& m, float& l,
                                            const float* vf, float score) {
    float mn = fmaxf(m, score);
    float al = __expf(m - mn);
    float p  = __expf(score - mn);
    l = l * al + p;
#pragma unroll
    for (int d = 0; d < 16; ++d) o[d] = fmaf(o[d], al, p * vf[d]);
    m = mn;
}

// ---------- kernel A: fused QKV projection + causal attention per (b,n,j) ----------
// LDS: Ks fp32 32 KB + Vs bf16 16 KB + weights bf16 12 KB = 60 KB.
__global__ __launch_bounds__(256) void qkv_attn_kernel(
        const float* __restrict__ x,
        const float* __restrict__ qm,
        const float* __restrict__ km,
        const float* __restrict__ vm,
        float* __restrict__ AO) {
    __shared__ __align__(16) float Ks[SS][HSS];           // 32 KB fp32
    __shared__ __align__(16) unsigned short Vs[SS][HSS];  // 16 KB bf16
    __shared__ __align__(16) unsigned short Wq[HH * HSS]; // 4 KB bf16
    __shared__ __align__(16) unsigned short Wk[HH * HSS]; // 4 KB
    __shared__ __align__(16) unsigned short Wv[HH * HSS]; // 4 KB

    int tid = threadIdx.x;
    int blk = blockIdx.x;           // (b*NH+n)*J + j
    int j  = blk % JJ;
    int nb = blk / JJ;
    int n  = nb % NHH;
    int b  = nb / NHH;

    // stage this (n,j)'s three 128x16 fp32 weight matrices into LDS as bf16
    size_t wbase = (size_t)(n * JJ + j) * HH * HSS;
    const float* gq = qm + wbase;
    const float* gk = km + wbase;
    const float* gv = vm + wbase;
    for (int i = tid; i < HH * HSS; i += 256) {
        Wq[i] = f2b(gq[i]); Wk[i] = f2b(gk[i]); Wv[i] = f2b(gv[i]);
    }
    __syncthreads();

    int r1 = tid;            // rows 0..255
    int r2 = SS - 1 - tid;   // rows 511..256
    float q1[HSS], q2[HSS];
    const uint4* wq4 = (const uint4*)Wq;   // row h = wq4[2h], wq4[2h+1]
    const uint4* wk4 = (const uint4*)Wk;
    const uint4* wv4 = (const uint4*)Wv;

    for (int rr = 0; rr < 2; ++rr) {
        int r = rr ? r2 : r1;
        float qa[16], ka[16], va[16];
#pragma unroll
        for (int d = 0; d < 16; ++d) { qa[d] = 0.f; ka[d] = 0.f; va[d] = 0.f; }
        const float4* xp = (const float4*)(x + ((size_t)((b * SS + r) * JJ + j)) * HH);
        for (int h8 = 0; h8 < HH / 8; ++h8) {
            float4 xa = xp[2 * h8], xb = xp[2 * h8 + 1];
            float xs[8] = {xa.x, xa.y, xa.z, xa.w, xb.x, xb.y, xb.z, xb.w};
#pragma unroll
            for (int hh = 0; hh < 8; ++hh) {
                int h = h8 * 8 + hh;
                float xv = xs[hh];
                fma16v(wq4[2 * h], wq4[2 * h + 1], xv, qa);
                fma16v(wk4[2 * h], wk4[2 * h + 1], xv, ka);
                fma16v(wv4[2 * h], wv4[2 * h + 1], xv, va);
            }
        }
#pragma unroll
        for (int d = 0; d < 16; ++d) Ks[r][d] = ka[d];
#pragma unroll
        for (int d = 0; d < 16; ++d) Vs[r][d] = f2b(va[d]);
        float* qd = rr ? q2 : q1;
#pragma unroll
        for (int d = 0; d < 16; ++d) qd[d] = qa[d];
    }
    __syncthreads();

    float o1[16], o2[16];
#pragma unroll
    for (int d = 0; d < 16; ++d) { o1[d] = 0.f; o2[d] = 0.f; }
    float m1 = -1e30f, l1 = 0.f, m2 = -1e30f, l2 = 0.f;

    for (int tt = 0; tt < SS; ++tt) {
        float kf[16], vf[16];
#pragma unroll
        for (int d = 0; d < 4; ++d) {
            float4 kk = ((const float4*)Ks[tt])[d];
            kf[4*d] = kk.x; kf[4*d+1] = kk.y; kf[4*d+2] = kk.z; kf[4*d+3] = kk.w;
        }
        uint4 v0 = ((const uint4*)&Vs[tt][0])[0];
        uint4 v1 = ((const uint4*)&Vs[tt][0])[1];
        unpack2(v0.x, vf[0],  vf[1]);  unpack2(v0.y, vf[2],  vf[3]);
        unpack2(v0.z, vf[4],  vf[5]);  unpack2(v0.w, vf[6],  vf[7]);
        unpack2(v1.x, vf[8],  vf[9]);  unpack2(v1.y, vf[10], vf[11]);
        unpack2(v1.z, vf[12], vf[13]); unpack2(v1.w, vf[14], vf[15]);
        if (tt <= r1) {
            float dp = 0.f;
#pragma unroll
            for (int d = 0; d < 16; ++d) dp = fmaf(q1[d], kf[d], dp);
            attn_update(o1, m1, l1, vf, dp * 0.25f);   // 1/sqrt(HS)=0.25
        }
        if (tt <= r2) {
            float dp = 0.f;
#pragma unroll
            for (int d = 0; d < 16; ++d) dp = fmaf(q2[d], kf[d], dp);
            attn_update(o2, m2, l2, vf, dp * 0.25f);
        }
    }
    // AO layout: (b, s, j, n*HS+d) fp32
    float inv1 = 1.0f / l1, inv2 = 1.0f / l2;
    float* out1 = AO + ((size_t)((b * SS + r1) * JJ + j)) * HH + n * HSS;
    float* out2 = AO + ((size_t)((b * SS + r2) * JJ + j)) * HH + n * HSS;
#pragma unroll
    for (int d = 0; d < 16; ++d) {
        out1[d] = o1[d] * inv1;
        out2[d] = o2[d] * inv2;
    }
}

// ---------- kernel B: output projection + residual + LayerNorm (fp32 out) ----------
__global__ __launch_bounds__(256) void proj_ln_kernel(
        const float* __restrict__ AO, const float* __restrict__ x,
        const float* __restrict__ proj,
        const float* __restrict__ gamma, const float* __restrict__ beta,
        float* __restrict__ out) {
    __shared__ float aoS[8][HH];        // 4 KB
    __shared__ float meanS[8], rstdS[8];
    int blk   = blockIdx.x;             // (b*J + j)*(S/8) + stile
    int stile = blk % (SS / 8);
    int t2    = blk / (SS / 8);
    int j = t2 % JJ;
    int b = t2 / JJ;
    int s0  = stile * 8;
    int tid = threadIdx.x;

    for (int i = tid; i < 8 * HH; i += 256) {
        int lr = i >> 7, k2 = i & 127;
        aoS[lr][k2] = AO[((size_t)((b * SS + s0 + lr) * JJ + j)) * HH + k2];
    }
    __syncthreads();

    int k  = tid & 127;
    int rg = tid >> 7;                  // rows rg, rg+2, rg+4, rg+6
    float acc[4] = {0.f, 0.f, 0.f, 0.f};
    const float* pjp = proj + (size_t)j * HH * HH;
    for (int h = 0; h < HH; ++h) {
        float w = pjp[h * HH + k];      // proj[j,h,k], coalesced over k
#pragma unroll
        for (int i = 0; i < 4; ++i) acc[i] = fmaf(aoS[rg + 2 * i][h], w, acc[i]);
    }
    float val[4];
#pragma unroll
    for (int i = 0; i < 4; ++i) {
        int srow = s0 + rg + 2 * i;
        val[i] = acc[i] + x[((size_t)((b * SS + srow) * JJ + j)) * HH + k];
    }
    __syncthreads();                    // everyone done reading aoS
#pragma unroll
    for (int i = 0; i < 4; ++i) aoS[rg + 2 * i][k] = val[i];
    __syncthreads();

    // LN reductions: 32 lanes per row
    int row = tid >> 5, l32 = tid & 31;
    float s1 = 0.f, s2 = 0.f;
#pragma unroll
    for (int c = 0; c < 4; ++c) {
        float v = aoS[row][l32 + 32 * c];
        s1 += v; s2 += v * v;
    }
#pragma unroll
    for (int mdel = 16; mdel >= 1; mdel >>= 1) {
        s1 += __shfl_xor(s1, mdel, 64);
        s2 += __shfl_xor(s2, mdel, 64);
    }
    if (l32 == 0) {
        float mu  = s1 * (1.0f / 128.0f);
        float var = s2 * (1.0f / 128.0f) - mu * mu;
        meanS[row] = mu;
        rstdS[row] = rsqrtf(var + 1e-5f);
    }
    __syncthreads();
    float g  = gamma[k];
    float bt = beta[k];
#pragma unroll
    for (int i = 0; i < 4; ++i) {
        int lr = rg + 2 * i;
        float o = (val[i] - meanS[lr]) * rstdS[lr] * g + bt;
        out[((size_t)((b * SS + s0 + lr) * JJ + j)) * HH + k] = o;   // fp32 output
    }
}

extern "C" void kernel_launch(void* const* d_in, const int* in_sizes, int n_in,
                              void* d_out, int out_size, void* d_ws, size_t ws_size,
                              hipStream_t stream) {
    // Inputs identified by element count (robust to mask presence/absence):
    //   x = B*S*J*H = 6,291,456 ; mask = S*S = 262,144 (causal, implemented directly)
    //   q_mat,k_mat,v_mat,attn_proj = 393,216 each (dict order preserved)
    //   ln_gamma, ln_beta = 128 each (fallback gamma=1, beta=0 if absent)
    const int NX  = BB * SS * JJ * HH;     // 6,291,456
    const int NMK = SS * SS;               // 262,144
    const int NW  = NHH * JJ * HH * HSS;   // 393,216 (== JJ*HH*HH)
    const float* x = nullptr;
    const float* w4[4] = {nullptr, nullptr, nullptr, nullptr};
    const float* p128[2] = {nullptr, nullptr};
    int nW = 0, n128 = 0;
    for (int i = 0; i < n_in; ++i) {
        int s = in_sizes[i];
        const float* p = (const float*)d_in[i];
        if      (s == NX)   { if (!x) x = p; }
        else if (s == NMK)  { /* mask */ }
        else if (s == NW)   { if (nW < 4)  w4[nW++] = p; }
        else if (s == HH)   { if (n128 < 2) p128[n128++] = p; }
    }
    const float* qm = w4[0];
    const float* km = w4[1];
    const float* vm = w4[2];
    const float* pj = w4[3];
    float* out = (float*)d_out;            // reference output dtype: float32

    // ws layout: AO fp32 (25.2 MB) + gamma(128) + beta(128)
    float* AO = (float*)d_ws;
    float* gb = AO + (size_t)NX;
    float* bb = gb + HH;

    ln_param_kernel<<<1, 128, 0, stream>>>(p128[0], p128[1], gb, bb);
    qkv_attn_kernel<<<BB * NHH * JJ, 256, 0, stream>>>(x, qm, km, vm, AO);
    proj_ln_kernel<<<BB * JJ * (SS / 8), 256, 0, stream>>>(AO, x, pj, gb, bb, out);
}